// Round 14
// baseline (335.128 us; speedup 1.0000x reference)
//
#include <hip/hip_runtime.h>

#define B_ 16
#define N_ 16384
#define K_ 16

// ---- workspace layout (float offsets) ----
enum : int {
  WS_LAT  = 0,      // 32 x 128 latent (f32, atomicMax-as-uint, relu>=0)
  WS_SEL  = 5632,   // 32 x 48 selected keypoints
  WS_PMIN = 7168,   // 16 x 3
  WS_PMAX = 7216,   // 16 x 3
  WS_CF   = 7264,   // (unused; cage corners computed in deform)
  WS_W1F  = 31840,  // 64 x 3  bn-folded (fp32)
  WS_B1F  = 32032,  // 64
  // split-f16 B-fragment tables (32x32x16 MFMA layout), built by prep:
  WS_WB2H = 32096,  // 8192 f16: layer2 B hi frags [wn*4+kt][lane][8]
  WS_WB2L = 36192,  // 8192 f16
  WS_B2F  = 40288,  // 128 fp32 folded bias
  WS_WB3H = 40416,  // 16384 f16: layer3 B hi frags [wn*8+kt][lane][8]
  WS_B3F  = 56800,  // 128 fp32 folded bias
  WS_WB3L = 56928,  // 16384 f16
  WS_END  = 73312
};

enum : int { OUT_DEF=0, OUT_SRCKP=786432, OUT_TGTKP=787200 };

typedef _Float16 f16x8 __attribute__((ext_vector_type(8)));
typedef _Float16 f16x2 __attribute__((ext_vector_type(2)));
typedef float    f32x16 __attribute__((ext_vector_type(16)));

__device__ __forceinline__ float dist2rn(float px,float py,float pz,float sx,float sy,float sz){
  float dx=__fsub_rn(px,sx), dy=__fsub_rn(py,sy), dz=__fsub_rn(pz,sz);
  return __fadd_rn(__fadd_rn(__fmul_rn(dx,dx),__fmul_rn(dy,dy)),__fmul_rn(dz,dz));
}

// ---------------- prep: fold BN into encoder weights + split-f16 frags --------
struct EncW {
  const float *w1,*b1,*g1,*be1,*m1,*v1;
  const float *w2,*b2,*g2,*be2,*m2,*v2;
  const float *w3,*b3,*g3,*be3,*m3,*v3;
};

__device__ __forceinline__ float bn_scale(const float* g, const float* v, int ch){
  return g[ch] * (1.0f / sqrtf(v[ch] + 1e-5f));
}

__global__ void prep_kernel(EncW a, float* ws){
  const int stride = gridDim.x*blockDim.x;
  const int tid = blockIdx.x*blockDim.x + threadIdx.x;
  for (int i=tid;i<4096;i+=stride)            // zero latent (atomicMax target)
    ws[WS_LAT+i] = 0.0f;
  for (int i=tid;i<192;i+=stride){            // W1F
    int o=i/3;
    ws[WS_W1F+i] = a.w1[i] * bn_scale(a.g1,a.v1,o);
  }
  for (int i=tid;i<64;i+=stride){             // B1F
    float s = bn_scale(a.g1,a.v1,i);
    ws[WS_B1F+i] = (a.b1[i] - a.m1[i])*s + a.be1[i];
  }
  // layer2 B-frags for 32x32x16: lane l holds B[k=kt*16+(l>>5)*8+j][col=wn*32+(l&31)]
  for (int i=tid;i<8192;i+=stride){
    int j = i & 7, frag = i >> 3;
    int l = frag & 63, wk = frag >> 6;        // wk = wn*4 + kt, <16
    int kt = wk & 3, wn = wk >> 2;
    int c = kt*16 + ((l>>5)<<3) + j;          // 0..63 in-channel (K)
    int o = wn*32 + (l&31);                   // 0..127 out-channel (N)
    float v = a.w2[o*64+c] * bn_scale(a.g2,a.v2,o);
    _Float16 h = (_Float16)v;
    ((_Float16*)(ws+WS_WB2H))[i] = h;
    ((_Float16*)(ws+WS_WB2L))[i] = (_Float16)(v - (float)h);
  }
  for (int i=tid;i<128;i+=stride){
    float s = bn_scale(a.g2,a.v2,i);
    ws[WS_B2F+i] = (a.b2[i] - a.m2[i])*s + a.be2[i];
  }
  // layer3 B-frags (16384 elements = 128x128)
  for (int i=tid;i<16384;i+=stride){
    int j = i & 7, frag = i >> 3;
    int l = frag & 63, wk = frag >> 6;        // wk = wn*8 + kt, <32
    int kt = wk & 7, wn = wk >> 3;
    int c = kt*16 + ((l>>5)<<3) + j;          // 0..127 in-channel (K)
    int o = wn*32 + (l&31);                   // 0..127 out-channel (N)
    float v = a.w3[o*128+c] * bn_scale(a.g3,a.v3,o);
    _Float16 h = (_Float16)v;
    ((_Float16*)(ws+WS_WB3H))[i] = h;
    ((_Float16*)(ws+WS_WB3L))[i] = (_Float16)(v - (float)h);
  }
  for (int i=tid;i<128;i+=stride){
    float s = bn_scale(a.g3,a.v3,i);
    ws[WS_B3F+i] = (a.b3[i] - a.m3[i])*s + a.be3[i];
  }
}

// ---------------- encoder v15: 2-tile software pipeline -----------------------
// R13 post-mortem: encode pinned at ~100us with MfmaUtil 33 / VALUBusy 35 —
// neither pipe is the limit; the rest is barrier-drain (3 full barriers/tile,
// both pipes idle during drain). v15 processes TWO tiles per block (2x32KB LDS)
// with phases interleaved so each barrier region pairs MFMA(one tile) with
// VALU/LDS work(other tile); 4 barriers per 2 tiles instead of 6. Per-tile
// arithmetic chains byte-identical to v14 -> bit-identical latent.

__device__ __forceinline__ void enc_layer1(const float* __restrict__ base,
                                           _Float16* __restrict__ Abuf,
                                           const float* __restrict__ ws, int t){
  const int pt = t >> 2, q = t & 3;        // pt 0..63
  const float x = base[pt*3+0], y = base[pt*3+1], z = base[pt*3+2];
  const float* w1 = ws + WS_W1F;
  const float* b1 = ws + WS_B1F;
  const int swz1 = (pt & 7) << 3;
  _Float16* AH1 = Abuf;
  _Float16* AL1 = Abuf + 4096;
  #pragma unroll
  for (int cc = 0; cc < 16; cc += 2){
    const int o = q*16 + cc;
    float v0 = fmaf(w1[o*3+2], z, fmaf(w1[o*3+1], y, w1[o*3+0]*x)) + b1[o];
    float v1 = fmaf(w1[o*3+5], z, fmaf(w1[o*3+4], y, w1[o*3+3]*x)) + b1[o+1];
    v0 = fmaxf(v0, 0.0f); v1 = fmaxf(v1, 0.0f);
    f16x2 h, l;
    h[0] = (_Float16)v0;              h[1] = (_Float16)v1;
    l[0] = (_Float16)(v0 - (float)h[0]); l[1] = (_Float16)(v1 - (float)h[1]);
    const int idx = (pt*64 + o) ^ swz1;
    *(f16x2*)&AH1[idx] = h;
    *(f16x2*)&AL1[idx] = l;
  }
}

__device__ __forceinline__ void enc_layer2(const _Float16* __restrict__ Abuf,
                                           const f16x8 b2h[4], const f16x8 b2l[4],
                                           const int koff[8], int l31,
                                           f32x16 acc2[2]){
  #pragma unroll
  for (int e=0;e<16;e++){ acc2[0][e]=0.0f; acc2[1][e]=0.0f; }
  const char* pA2 = (const char*)Abuf + l31*128;
  #pragma unroll
  for (int kt=0; kt<4; kt++){
    #pragma unroll
    for (int m=0;m<2;m++){
      const f16x8 ah = *(const f16x8*)(pA2 + m*4096 + koff[kt]);
      const f16x8 al = *(const f16x8*)(pA2 + m*4096 + koff[kt] + 8192);
      acc2[m] = __builtin_amdgcn_mfma_f32_32x32x16_f16(ah, b2h[kt], acc2[m], 0,0,0);
      acc2[m] = __builtin_amdgcn_mfma_f32_32x32x16_f16(ah, b2l[kt], acc2[m], 0,0,0);
      acc2[m] = __builtin_amdgcn_mfma_f32_32x32x16_f16(al, b2h[kt], acc2[m], 0,0,0);
    }
  }
}

__device__ __forceinline__ void enc_h2store(_Float16* __restrict__ Abuf,
                                            const f32x16 acc2[2],
                                            const float* __restrict__ ws,
                                            int ch, int hb){
  const float b = ws[WS_B2F + ch];
  char* pWr[4];
  #pragma unroll
  for (int r4=0;r4<4;r4++)
    pWr[r4] = (char*)Abuf + (r4 + 4*hb)*256 + ((ch ^ ((r4 + 4*hb) << 3)) << 1);
  #pragma unroll
  for (int r4=0;r4<4;r4++){
    #pragma unroll
    for (int rq=0;rq<4;rq++){
      const int reg = rq*4 + r4;
      #pragma unroll
      for (int m=0;m<2;m++){
        const float v = fmaxf(acc2[m][reg] + b, 0.0f);
        const _Float16 hi = (_Float16)v;
        const _Float16 lo = (_Float16)(v - (float)hi);
        char* pw = pWr[r4] + rq*2048 + m*8192;
        *(_Float16*)(pw) = hi;
        *(_Float16*)(pw + 16384) = lo;
      }
    }
  }
}

__device__ __forceinline__ void enc_layer3(const _Float16* __restrict__ Abuf,
                                           const float* __restrict__ ws,
                                           const int koff[8], int l31, int wn, int lane,
                                           f32x16 acc3[2]){
  #pragma unroll
  for (int e=0;e<16;e++){ acc3[0][e]=0.0f; acc3[1][e]=0.0f; }
  const _Float16* wb3h = (const _Float16*)(ws + WS_WB3H);
  const _Float16* wb3l = (const _Float16*)(ws + WS_WB3L);
  const char* pA3 = (const char*)Abuf + l31*256;
  #pragma unroll
  for (int kt=0; kt<8; kt++){
    const int fi = ((wn*8 + kt)*64 + lane)*8;
    const f16x8 bh = *(const f16x8*)(wb3h + fi);
    const f16x8 bl = *(const f16x8*)(wb3l + fi);
    #pragma unroll
    for (int m=0;m<2;m++){
      const f16x8 ah = *(const f16x8*)(pA3 + m*8192 + koff[kt]);
      const f16x8 al = *(const f16x8*)(pA3 + m*8192 + koff[kt] + 16384);
      acc3[m] = __builtin_amdgcn_mfma_f32_32x32x16_f16(ah, bh, acc3[m], 0,0,0);
      acc3[m] = __builtin_amdgcn_mfma_f32_32x32x16_f16(ah, bl, acc3[m], 0,0,0);
      acc3[m] = __builtin_amdgcn_mfma_f32_32x32x16_f16(al, bh, acc3[m], 0,0,0);
    }
  }
}

__device__ __forceinline__ void enc_epilogue(const f32x16 acc3[2],
                                             const float* __restrict__ ws,
                                             float* __restrict__ lat,
                                             int ch, int lane, int cloud){
  const float b = ws[WS_B3F + ch];
  float x = 0.0f;
  #pragma unroll
  for (int m=0;m<2;m++){
    #pragma unroll
    for (int r=0;r<16;r++)
      x = fmaxf(x, acc3[m][r] + b);
  }
  x = fmaxf(x, __shfl_xor(x, 32, 64));
  if (lane < 32)
    atomicMax((unsigned*)(lat + cloud*128 + ch), __float_as_uint(x));
}

__global__ __launch_bounds__(256, 2) void encode_kernel(const float* __restrict__ src,
                                                        const float* __restrict__ tgt,
                                                        const float* __restrict__ ws,
                                                        float* __restrict__ lat){
  const int cloud = blockIdx.y;
  const int t = threadIdx.x;
  const int lane = t & 63;
  const int wn = __builtin_amdgcn_readfirstlane(t >> 6);   // 0..3: cols wn*32..+31
  const int l31 = lane & 31;
  const int hb  = lane >> 5;
  const int swz = (l31 & 7) << 3;
  const int ch = wn*32 + l31;

  __shared__ alignas(16) _Float16 A0[16384];  // 32KB tile buffer 0
  __shared__ alignas(16) _Float16 A1[16384];  // 32KB tile buffer 1

  const float* cbase = (cloud < B_) ? (src + (size_t)cloud*N_*3)
                                    : (tgt + (size_t)(cloud-B_)*N_*3);
  const float* base0 = cbase + (size_t)(blockIdx.x*2    )*64*3;
  const float* base1 = cbase + (size_t)(blockIdx.x*2 + 1)*64*3;

  // prefetch layer2 B-frags (shared by both tiles)
  f16x8 b2h[4], b2l[4];
  {
    const _Float16* wb2h = (const _Float16*)(ws + WS_WB2H);
    const _Float16* wb2l = (const _Float16*)(ws + WS_WB2L);
    #pragma unroll
    for (int kt=0; kt<4; kt++){
      const int fi = ((wn*4 + kt)*64 + lane)*8;
      b2h[kt] = *(const f16x8*)(wb2h + fi);
      b2l[kt] = *(const f16x8*)(wb2l + fi);
    }
  }

  int koff[8];
  #pragma unroll
  for (int kt=0; kt<8; kt++) koff[kt] = (((kt*16) | (hb*8)) ^ swz) << 1;

  // ---- pipeline: 4 barriers per 2 tiles ----
  enc_layer1(base0, A0, ws, t);
  __syncthreads();                          // #1: A0 h1 ready

  f32x16 acc2a[2];
  enc_layer2(A0, b2h, b2l, koff, l31, acc2a);   // MFMA on A0
  enc_layer1(base1, A1, ws, t);                 // VALU on A1 (independent)
  __syncthreads();                          // #2: A0 h1 reads done; A1 h1 ready

  enc_h2store(A0, acc2a, ws, ch, hb);           // overlay A0
  f32x16 acc2b[2];
  enc_layer2(A1, b2h, b2l, koff, l31, acc2b);   // MFMA on A1
  __syncthreads();                          // #3: A0 h2 visible; A1 h1 reads done

  f32x16 acc3a[2];
  enc_layer3(A0, ws, koff, l31, wn, lane, acc3a);  // MFMA on A0
  enc_h2store(A1, acc2b, ws, ch, hb);              // overlay A1
  __syncthreads();                          // #4: A1 h2 visible

  f32x16 acc3b[2];
  enc_layer3(A1, ws, koff, l31, wn, lane, acc3b);  // MFMA on A1
  enc_epilogue(acc3a, ws, lat, ch, lane, cloud);   // VALU+atomic on T0
  enc_epilogue(acc3b, ws, lat, ch, lane, cloud);
}

// ---------------- FPS v5 (unchanged from R13, passing) -------------------------
__device__ __forceinline__ void fps_round(int r, int t, int wv,
                                          float bv, int bi, float bx, float by, float bz,
                                          float (*cv)[16], int (*ci)[16],
                                          float (*cx)[16], float (*cy)[16], float (*cz)[16],
                                          float* ws, float* out, int cloud,
                                          float& s0, float& s1, float& s2){
  float v = bv; int i = bi;
  #pragma unroll
  for (int m=1;m<64;m<<=1){
    float v2=__shfl_xor(v,m,64); int i2=__shfl_xor(i,m,64);
    if (v2 > v || (v2 == v && i2 < i)){ v=v2; i=i2; }
  }
  const int p = r & 1;
  if ((i >> 4) == t){ cv[p][wv]=v; ci[p][wv]=i; cx[p][wv]=bx; cy[p][wv]=by; cz[p][wv]=bz; }
  __syncthreads();
  float wvv = cv[p][0]; int wi = ci[p][0]; int slot = 0;
  #pragma unroll
  for (int e=1;e<16;e++){
    float v2=cv[p][e]; int i2=ci[p][e];
    if (v2 > wvv || (v2 == wvv && i2 < wi)){ wvv=v2; wi=i2; slot=e; }
  }
  s0 = cx[p][slot]; s1 = cy[p][slot]; s2 = cz[p][slot];
  if (t == 0){
    float* sw = ws + WS_SEL + cloud*48 + r*3;
    sw[0]=s0; sw[1]=s1; sw[2]=s2;
    size_t o = (cloud<B_) ? (size_t)(OUT_SRCKP + cloud*48 + r*3)
                          : (size_t)(OUT_TGTKP + (cloud-B_)*48 + r*3);
    out[o]=s0; out[o+1]=s1; out[o+2]=s2;
  }
}

__global__ __launch_bounds__(1024, 4) void fps_kernel(const float* __restrict__ src,
                                                      const float* __restrict__ tgt,
                                                      const float* __restrict__ kw1,
                                                      const float* __restrict__ kb1,
                                                      const float* __restrict__ kw2,
                                                      const float* __restrict__ kb2,
                                                      float* ws, float* out){
  const int cloud = blockIdx.x; const int t = threadIdx.x;
  const int wv = t >> 6;
  const int lane = t & 63;
  const float* base = (cloud < B_) ? (src + (size_t)cloud*N_*3)
                                   : (tgt + (size_t)cloud*N_*3 - (size_t)B_*N_*3);
  __shared__ alignas(16) float kpl[48];
  __shared__ alignas(16) float h[128];
  __shared__ float cv[2][16]; __shared__ int ci[2][16];
  __shared__ float cx[2][16]; __shared__ float cy[2][16]; __shared__ float cz[2][16];
  __shared__ float red[96];

  // load 16 consecutive points/thread via 12 float4 (coalesced)
  float px[16], py[16], pz[16];
  {
    float4 raw[12];
    const float4* b4 = (const float4*)(base + (size_t)t*48);
    #pragma unroll
    for (int q=0;q<12;q++) raw[q] = b4[q];
    #pragma unroll
    for (int q=0;q<4;q++){
      float4 va=raw[q*3], vb=raw[q*3+1], vc=raw[q*3+2];
      px[q*4  ]=va.x; py[q*4  ]=va.y; pz[q*4  ]=va.z;
      px[q*4+1]=va.w; py[q*4+1]=vb.x; pz[q*4+1]=vb.y;
      px[q*4+2]=vb.z; py[q*4+2]=vb.w; pz[q*4+2]=vc.x;
      px[q*4+3]=vc.y; py[q*4+3]=vc.z; pz[q*4+3]=vc.w;
    }
  }
  // pin point state in VGPRs: opaque to the compiler -> no remat-by-reload
  #pragma unroll
  for (int k=0;k<16;k++){
    asm volatile("" : "+v"(px[k]), "+v"(py[k]), "+v"(pz[k]));
  }

  // kp-MLP layer1 (order-identical; float4-batched loads)
  const float* lat = ws + WS_LAT + cloud*128;
  if (t < 128){
    float acc = kb1[t];
    const float4* w4 = (const float4*)(kw1 + t*128);
    const float4* l4 = (const float4*)lat;
    #pragma unroll 8
    for (int c4=0;c4<32;c4++){
      float4 wq=w4[c4], lq=l4[c4];
      acc = fmaf(lq.x, wq.x, acc);
      acc = fmaf(lq.y, wq.y, acc);
      acc = fmaf(lq.z, wq.z, acc);
      acc = fmaf(lq.w, wq.w, acc);
    }
    h[t] = fmaxf(acc, 0.0f);
  }
  __syncthreads();
  if (t < 48){
    float acc = kb2[t];
    const float4* w4 = (const float4*)(kw2 + t*128);
    #pragma unroll 8
    for (int c4=0;c4<32;c4++){
      float4 wq=w4[c4];
      float4 hq=*(const float4*)&h[c4*4];
      acc = fmaf(hq.x, wq.x, acc);
      acc = fmaf(hq.y, wq.y, acc);
      acc = fmaf(hq.z, wq.z, acc);
      acc = fmaf(hq.w, wq.w, acc);
    }
    kpl[t] = acc;
  }

  // src cloud min/max (exact: fmin/fmax order-independent)
  if (cloud < B_){
    float mn0=3.4e38f,mn1=3.4e38f,mn2=3.4e38f, mx0=-3.4e38f,mx1=-3.4e38f,mx2=-3.4e38f;
    #pragma unroll
    for (int k=0;k<16;k++){
      mn0=fminf(mn0,px[k]); mn1=fminf(mn1,py[k]); mn2=fminf(mn2,pz[k]);
      mx0=fmaxf(mx0,px[k]); mx1=fmaxf(mx1,py[k]); mx2=fmaxf(mx2,pz[k]);
    }
    #pragma unroll
    for (int m=1;m<64;m<<=1){
      mn0=fminf(mn0,__shfl_xor(mn0,m,64)); mx0=fmaxf(mx0,__shfl_xor(mx0,m,64));
      mn1=fminf(mn1,__shfl_xor(mn1,m,64)); mx1=fmaxf(mx1,__shfl_xor(mx1,m,64));
      mn2=fminf(mn2,__shfl_xor(mn2,m,64)); mx2=fmaxf(mx2,__shfl_xor(mx2,m,64));
    }
    if (lane==0){
      red[wv*6+0]=mn0; red[wv*6+1]=mn1; red[wv*6+2]=mn2;
      red[wv*6+3]=mx0; red[wv*6+4]=mx1; red[wv*6+5]=mx2;
    }
    __syncthreads();
    if (t < 6){
      float v = red[t];
      for (int e=1;e<16;e++){
        float v2 = red[e*6+t];
        v = (t<3) ? fminf(v,v2) : fmaxf(v,v2);
      }
      if (t<3) ws[WS_PMIN + cloud*3 + t] = v;
      else     ws[WS_PMAX + cloud*3 + (t-3)] = v;
    }
  }
  __syncthreads();   // kpl ready for all; red/minmax done

  // dmin over 16 keypoints, j-outer
  float mind[16];
  #pragma unroll
  for (int k=0;k<16;k++) mind[k] = 3.4028235e38f;
  for (int j=0;j<K_;j++){
    const float sx=kpl[j*3], sy=kpl[j*3+1], sz=kpl[j*3+2];
    #pragma unroll
    for (int k=0;k<16;k++)
      mind[k] = fminf(mind[k], dist2rn(px[k],py[k],pz[k], sx,sy,sz));
  }

  // round 0: argmax of keypoint-dmin
  float bv = -1.0f; int bi = 0; float bx=0.f, by=0.f, bz=0.f;
  #pragma unroll
  for (int k=0;k<16;k++){
    if (mind[k] > bv){ bv=mind[k]; bi=t*16+k; bx=px[k]; by=py[k]; bz=pz[k]; }
  }
  float s0, s1, s2;
  fps_round(0, t, wv, bv, bi, bx, by, bz, cv, ci, cx, cy, cz, ws, out, cloud, s0, s1, s2);

  // round 1: REPLACE (matches reference)
  bv = -1.0f; bi = 0;
  #pragma unroll
  for (int k=0;k<16;k++){
    float d = dist2rn(px[k],py[k],pz[k], s0,s1,s2);
    mind[k] = d;
    if (d > bv){ bv=d; bi=t*16+k; bx=px[k]; by=py[k]; bz=pz[k]; }
  }
  fps_round(1, t, wv, bv, bi, bx, by, bz, cv, ci, cx, cy, cz, ws, out, cloud, s0, s1, s2);

  // rounds 2..15
  for (int r=2; r<K_; ++r){
    bv = -1.0f; bi = 0;
    #pragma unroll
    for (int k=0;k<16;k++){
      float d = dist2rn(px[k],py[k],pz[k], s0,s1,s2);
      float m = fminf(mind[k], d);
      mind[k] = m;
      if (m > bv){ bv=m; bi=t*16+k; bx=px[k]; by=py[k]; bz=pz[k]; }
    }
    fps_round(r, t, wv, bv, bi, bx, by, bz, cv, ci, cx, cy, cz, ws, out, cloud, s0, s1, s2);
  }
}

// ---------------- cage MLP (redundant per block) + trilinear deform -----------
__global__ __launch_bounds__(256) void deform_kernel(const float* __restrict__ src,
                                                     const float* __restrict__ cw1,
                                                     const float* __restrict__ cb1,
                                                     const float* __restrict__ cw2,
                                                     const float* __restrict__ cb2,
                                                     const float* __restrict__ ws,
                                                     float* __restrict__ out){
  const int b = blockIdx.y;
  const int t = threadIdx.x;
  __shared__ float cf[1536];
  __shared__ alignas(16) float diff[48];
  __shared__ alignas(16) float hh[128];

  if (t<48) diff[t] = __fsub_rn(ws[WS_SEL + (B_+b)*48 + t], ws[WS_SEL + b*48 + t]);
  __syncthreads();
  if (t<128){
    const float4* w4 = (const float4*)(cw1 + t*48);
    float acc = cb1[t];
    #pragma unroll
    for (int j4=0;j4<12;j4++){
      float4 wq=w4[j4];
      float4 dq=*(const float4*)&diff[j4*4];
      acc = fmaf(dq.x, wq.x, acc);
      acc = fmaf(dq.y, wq.y, acc);
      acc = fmaf(dq.z, wq.z, acc);
      acc = fmaf(dq.w, wq.w, acc);
    }
    hh[t] = fmaxf(acc, 0.0f);
  }
  __syncthreads();
  for (int o = t; o < 1536; o += 256){
    const float4* w4 = (const float4*)(cw2 + o*128);
    float acc = cb2[o];
    #pragma unroll 8
    for (int c4=0;c4<32;c4++){
      float4 wq=w4[c4];
      float4 hq=*(const float4*)&hh[c4*4];
      acc = fmaf(hq.x, wq.x, acc);
      acc = fmaf(hq.y, wq.y, acc);
      acc = fmaf(hq.z, wq.z, acc);
      acc = fmaf(hq.w, wq.w, acc);
    }
    int flat = o/3, coord = o - flat*3;
    int u = flat>>6, v=(flat>>3)&7, z=flat&7;
    int g = (coord==0)?u:((coord==1)?v:z);
    float gv = (g==7)?1.0f:(float)g*(1.0f/7.0f);
    cf[o] = gv + acc;
  }
  __syncthreads();

  const float mn0 = ws[WS_PMIN+b*3+0], mn1 = ws[WS_PMIN+b*3+1], mn2 = ws[WS_PMIN+b*3+2];
  const float mx0 = ws[WS_PMAX+b*3+0], mx1 = ws[WS_PMAX+b*3+1], mx2 = ws[WS_PMAX+b*3+2];

  #pragma unroll
  for (int k=0;k<4;k++){
    const int n = blockIdx.x*1024 + k*256 + t;
    const float* p = src + ((size_t)b*N_ + n)*3;
    float pt[3]; int id[3]; float w[3];
    #pragma unroll
    for (int c=0;c<3;c++){
      float pv = p[c];
      float mnv = (c==0)?mn0:((c==1)?mn1:mn2);
      float mxv = (c==0)?mx0:((c==1)?mx1:mx2);
      float denom = __fadd_rn(__fsub_rn(mxv, mnv), 1e-6f);
      float tc = __fmul_rn(__fdiv_rn(__fsub_rn(pv, mnv), denom), 7.0f);
      int ic = (int)tc; ic = min(max(ic,0),6);
      pt[c]=pv; id[c]=ic; w[c]=__fsub_rn(tc, (float)ic);
    }
    const int flat = (id[0]<<6) + (id[1]<<3) + id[2];
    const float* c000 = cf + flat*3;
    const float wx=w[0], wy=w[1], wz=w[2];
    const float ux=__fsub_rn(1.0f,wx), uy=__fsub_rn(1.0f,wy), uz=__fsub_rn(1.0f,wz);
    const float w000=__fmul_rn(__fmul_rn(ux,uy),uz);
    const float w100=__fmul_rn(__fmul_rn(wx,uy),uz);
    const float w010=__fmul_rn(__fmul_rn(ux,wy),uz);
    const float w110=__fmul_rn(__fmul_rn(wx,wy),uz);
    const float w001=__fmul_rn(__fmul_rn(ux,uy),wz);
    const float w101=__fmul_rn(__fmul_rn(wx,uy),wz);
    const float w011=__fmul_rn(__fmul_rn(ux,wy),wz);
    const float w111=__fmul_rn(__fmul_rn(wx,wy),wz);
    #pragma unroll
    for (int c=0;c<3;c++){
      float d = __fmul_rn(w000, c000[c]);
      d = __fadd_rn(d, __fmul_rn(w100, c000[192+c]));
      d = __fadd_rn(d, __fmul_rn(w010, c000[24+c]));
      d = __fadd_rn(d, __fmul_rn(w110, c000[216+c]));
      d = __fadd_rn(d, __fmul_rn(w001, c000[3+c]));
      d = __fadd_rn(d, __fmul_rn(w101, c000[195+c]));
      d = __fadd_rn(d, __fmul_rn(w011, c000[27+c]));
      d = __fadd_rn(d, __fmul_rn(w111, c000[219+c]));
      out[((size_t)b*N_+n)*3 + c] = __fadd_rn(pt[c], d);
    }
  }
}

// ---------------- launch ------------------------------------------------------
extern "C" void kernel_launch(void* const* d_in, const int* in_sizes, int n_in,
                              void* d_out, int out_size, void* d_ws, size_t ws_size,
                              hipStream_t stream){
  const float* src = (const float*)d_in[0];
  const float* tgt = (const float*)d_in[1];
  float* ws = (float*)d_ws;
  float* out = (float*)d_out;

  EncW ew;
  ew.w1 =(const float*)d_in[2];  ew.b1 =(const float*)d_in[3];
  ew.g1 =(const float*)d_in[4];  ew.be1=(const float*)d_in[5];
  ew.m1 =(const float*)d_in[6];  ew.v1 =(const float*)d_in[7];
  ew.w2 =(const float*)d_in[8];  ew.b2 =(const float*)d_in[9];
  ew.g2 =(const float*)d_in[10]; ew.be2=(const float*)d_in[11];
  ew.m2 =(const float*)d_in[12]; ew.v2 =(const float*)d_in[13];
  ew.w3 =(const float*)d_in[14]; ew.b3 =(const float*)d_in[15];
  ew.g3 =(const float*)d_in[16]; ew.be3=(const float*)d_in[17];
  ew.m3 =(const float*)d_in[18]; ew.v3 =(const float*)d_in[19];

  prep_kernel<<<128, 256, 0, stream>>>(ew, ws);
  encode_kernel<<<dim3(128,32), 256, 0, stream>>>(src, tgt, ws, ws + WS_LAT);
  fps_kernel<<<32, 1024, 0, stream>>>(src, tgt,
      (const float*)d_in[20], (const float*)d_in[21],
      (const float*)d_in[22], (const float*)d_in[23], ws, out);
  deform_kernel<<<dim3(16,16), 256, 0, stream>>>(src,
      (const float*)d_in[24], (const float*)d_in[25],
      (const float*)d_in[26], (const float*)d_in[27], ws, out);
}

// Round 15
// 295.674 us; speedup vs baseline: 1.1334x; 1.1334x over previous
//
#include <hip/hip_runtime.h>

#define B_ 16
#define N_ 16384
#define K_ 16

// ---- workspace layout (float offsets) ----
enum : int {
  WS_LAT  = 0,      // 32 x 128 latent (f32, atomicMax-as-uint, relu>=0)
  WS_SEL  = 5632,   // 32 x 48 selected keypoints
  WS_PMIN = 7168,   // 16 x 3
  WS_PMAX = 7216,   // 16 x 3
  WS_CF   = 7264,   // (unused; cage corners computed in deform)
  WS_W1F  = 31840,  // 64 x 3  bn-folded (fp32)
  WS_B1F  = 32032,  // 64
  // split-f16 B-fragment tables (32x32x16 MFMA layout), built by prep:
  WS_WB2H = 32096,  // 8192 f16: layer2 B hi frags [wn*4+kt][lane][8]
  WS_WB2L = 36192,  // 8192 f16
  WS_B2F  = 40288,  // 128 fp32 folded bias
  WS_WB3H = 40416,  // 16384 f16: layer3 B hi frags [wn*8+kt][lane][8]
  WS_B3F  = 56800,  // 128 fp32 folded bias
  WS_WB3L = 56928,  // 16384 f16
  WS_END  = 73312
};

enum : int { OUT_DEF=0, OUT_SRCKP=786432, OUT_TGTKP=787200 };

typedef _Float16 f16x8 __attribute__((ext_vector_type(8)));
typedef _Float16 f16x2 __attribute__((ext_vector_type(2)));
typedef float    f32x16 __attribute__((ext_vector_type(16)));

__device__ __forceinline__ float dist2rn(float px,float py,float pz,float sx,float sy,float sz){
  float dx=__fsub_rn(px,sx), dy=__fsub_rn(py,sy), dz=__fsub_rn(pz,sz);
  return __fadd_rn(__fadd_rn(__fmul_rn(dx,dx),__fmul_rn(dy,dy)),__fmul_rn(dz,dz));
}

// ---------------- prep: fold BN into encoder weights + split-f16 frags --------
struct EncW {
  const float *w1,*b1,*g1,*be1,*m1,*v1;
  const float *w2,*b2,*g2,*be2,*m2,*v2;
  const float *w3,*b3,*g3,*be3,*m3,*v3;
};

__device__ __forceinline__ float bn_scale(const float* g, const float* v, int ch){
  return g[ch] * (1.0f / sqrtf(v[ch] + 1e-5f));
}

__global__ void prep_kernel(EncW a, float* ws){
  const int stride = gridDim.x*blockDim.x;
  const int tid = blockIdx.x*blockDim.x + threadIdx.x;
  for (int i=tid;i<4096;i+=stride)            // zero latent (atomicMax target)
    ws[WS_LAT+i] = 0.0f;
  for (int i=tid;i<192;i+=stride){            // W1F
    int o=i/3;
    ws[WS_W1F+i] = a.w1[i] * bn_scale(a.g1,a.v1,o);
  }
  for (int i=tid;i<64;i+=stride){             // B1F
    float s = bn_scale(a.g1,a.v1,i);
    ws[WS_B1F+i] = (a.b1[i] - a.m1[i])*s + a.be1[i];
  }
  // layer2 B-frags for 32x32x16: lane l holds B[k=kt*16+(l>>5)*8+j][col=wn*32+(l&31)]
  for (int i=tid;i<8192;i+=stride){
    int j = i & 7, frag = i >> 3;
    int l = frag & 63, wk = frag >> 6;        // wk = wn*4 + kt, <16
    int kt = wk & 3, wn = wk >> 2;
    int c = kt*16 + ((l>>5)<<3) + j;          // 0..63 in-channel (K)
    int o = wn*32 + (l&31);                   // 0..127 out-channel (N)
    float v = a.w2[o*64+c] * bn_scale(a.g2,a.v2,o);
    _Float16 h = (_Float16)v;
    ((_Float16*)(ws+WS_WB2H))[i] = h;
    ((_Float16*)(ws+WS_WB2L))[i] = (_Float16)(v - (float)h);
  }
  for (int i=tid;i<128;i+=stride){
    float s = bn_scale(a.g2,a.v2,i);
    ws[WS_B2F+i] = (a.b2[i] - a.m2[i])*s + a.be2[i];
  }
  // layer3 B-frags (16384 elements = 128x128)
  for (int i=tid;i<16384;i+=stride){
    int j = i & 7, frag = i >> 3;
    int l = frag & 63, wk = frag >> 6;        // wk = wn*8 + kt, <32
    int kt = wk & 7, wn = wk >> 3;
    int c = kt*16 + ((l>>5)<<3) + j;          // 0..127 in-channel (K)
    int o = wn*32 + (l&31);                   // 0..127 out-channel (N)
    float v = a.w3[o*128+c] * bn_scale(a.g3,a.v3,o);
    _Float16 h = (_Float16)v;
    ((_Float16*)(ws+WS_WB3H))[i] = h;
    ((_Float16*)(ws+WS_WB3L))[i] = (_Float16)(v - (float)h);
  }
  for (int i=tid;i<128;i+=stride){
    float s = bn_scale(a.g3,a.v3,i);
    ws[WS_B3F+i] = (a.b3[i] - a.m3[i])*s + a.be3[i];
  }
}

// ---------------- encoder v14 (R13 best: ~100us, 5 blocks/CU) -----------------
// R14 post-mortem: 2-tile pipeline (64KB LDS, 2 blocks/CU) regressed to 144us —
// inter-block overlap at 5 blocks/CU already absorbs barrier drains; trading
// occupancy for intra-wave overlap is a net loss. v14 is the plateau winner.
__global__ __launch_bounds__(256, 5) void encode_kernel(const float* __restrict__ src,
                                                        const float* __restrict__ tgt,
                                                        const float* __restrict__ ws,
                                                        float* __restrict__ lat){
  const int cloud = blockIdx.y;
  const int tile  = blockIdx.x;              // 256 tiles/cloud, 64 pts each
  const int t = threadIdx.x;
  const int lane = t & 63;
  const int wn = __builtin_amdgcn_readfirstlane(t >> 6);   // 0..3: cols wn*32..+31
  const int l31 = lane & 31;
  const int hb  = lane >> 5;                 // 0/1: k-group / +4-row half
  const int swz = (l31 & 7) << 3;            // f16-index bits 3-5

  __shared__ alignas(16) _Float16 A[16384];  // 32KB

  const float* base = ((cloud < B_) ? (src + (size_t)cloud*N_*3)
                                    : (tgt + (size_t)(cloud-B_)*N_*3))
                      + (size_t)tile*64*3;

  // ---- prefetch layer2 B-frags (latency hides under layer1) ----
  f16x8 b2h[4], b2l[4];
  {
    const _Float16* wb2h = (const _Float16*)(ws + WS_WB2H);
    const _Float16* wb2l = (const _Float16*)(ws + WS_WB2L);
    #pragma unroll
    for (int kt=0; kt<4; kt++){
      const int fi = ((wn*4 + kt)*64 + lane)*8;
      b2h[kt] = *(const f16x8*)(wb2h + fi);
      b2l[kt] = *(const f16x8*)(wb2l + fi);
    }
  }

  // ---- layer 1 (3->64), fp32 VALU ----
  {
    const int pt = t >> 2, q = t & 3;        // pt 0..63
    const float x = base[pt*3+0], y = base[pt*3+1], z = base[pt*3+2];
    const float* w1 = ws + WS_W1F;
    const float* b1 = ws + WS_B1F;
    const int swz1 = (pt & 7) << 3;
    _Float16* AH1 = A;
    _Float16* AL1 = A + 4096;
    #pragma unroll
    for (int cc = 0; cc < 16; cc += 2){
      const int o = q*16 + cc;
      float v0 = fmaf(w1[o*3+2], z, fmaf(w1[o*3+1], y, w1[o*3+0]*x)) + b1[o];
      float v1 = fmaf(w1[o*3+5], z, fmaf(w1[o*3+4], y, w1[o*3+3]*x)) + b1[o+1];
      v0 = fmaxf(v0, 0.0f); v1 = fmaxf(v1, 0.0f);
      f16x2 h, l;
      h[0] = (_Float16)v0;              h[1] = (_Float16)v1;
      l[0] = (_Float16)(v0 - (float)h[0]); l[1] = (_Float16)(v1 - (float)h[1]);
      const int idx = (pt*64 + o) ^ swz1;
      *(f16x2*)&AH1[idx] = h;
      *(f16x2*)&AL1[idx] = l;
    }
  }

  int koff[8];
  #pragma unroll
  for (int kt=0; kt<8; kt++) koff[kt] = (((kt*16) | (hb*8)) ^ swz) << 1;

  __syncthreads();

  // ---- layer 2 (64->128): 3-term split, 32x32x16 ----
  f32x16 acc2[2];
  #pragma unroll
  for (int e=0;e<16;e++){ acc2[0][e]=0.0f; acc2[1][e]=0.0f; }
  {
    const char* pA2 = (const char*)A + l31*128;
    #pragma unroll
    for (int kt=0; kt<4; kt++){
      #pragma unroll
      for (int m=0;m<2;m++){
        const f16x8 ah = *(const f16x8*)(pA2 + m*4096 + koff[kt]);
        const f16x8 al = *(const f16x8*)(pA2 + m*4096 + koff[kt] + 8192);
        acc2[m] = __builtin_amdgcn_mfma_f32_32x32x16_f16(ah, b2h[kt], acc2[m], 0,0,0);
        acc2[m] = __builtin_amdgcn_mfma_f32_32x32x16_f16(ah, b2l[kt], acc2[m], 0,0,0);
        acc2[m] = __builtin_amdgcn_mfma_f32_32x32x16_f16(al, b2h[kt], acc2[m], 0,0,0);
      }
    }
  }
  __syncthreads();

  // ---- h2 = relu(acc2 + b2): split hi/lo -> LDS ----
  const int ch = wn*32 + l31;
  {
    const float b = ws[WS_B2F + ch];
    char* pWr[4];
    #pragma unroll
    for (int r4=0;r4<4;r4++)
      pWr[r4] = (char*)A + (r4 + 4*hb)*256 + ((ch ^ ((r4 + 4*hb) << 3)) << 1);
    #pragma unroll
    for (int r4=0;r4<4;r4++){
      #pragma unroll
      for (int rq=0;rq<4;rq++){
        const int reg = rq*4 + r4;
        #pragma unroll
        for (int m=0;m<2;m++){
          const float v = fmaxf(acc2[m][reg] + b, 0.0f);
          const _Float16 hi = (_Float16)v;
          const _Float16 lo = (_Float16)(v - (float)hi);
          char* pw = pWr[r4] + rq*2048 + m*8192;
          *(_Float16*)(pw) = hi;
          *(_Float16*)(pw + 16384) = lo;
        }
      }
    }
  }
  __syncthreads();

  // ---- layer 3 (128->128): 3-term split, 32x32x16 ----
  f32x16 acc3[2];
  #pragma unroll
  for (int e=0;e<16;e++){ acc3[0][e]=0.0f; acc3[1][e]=0.0f; }
  {
    const _Float16* wb3h = (const _Float16*)(ws + WS_WB3H);
    const _Float16* wb3l = (const _Float16*)(ws + WS_WB3L);
    const char* pA3 = (const char*)A + l31*256;
    #pragma unroll
    for (int kt=0; kt<8; kt++){
      const int fi = ((wn*8 + kt)*64 + lane)*8;
      const f16x8 bh = *(const f16x8*)(wb3h + fi);
      const f16x8 bl = *(const f16x8*)(wb3l + fi);
      #pragma unroll
      for (int m=0;m<2;m++){
        const f16x8 ah = *(const f16x8*)(pA3 + m*8192 + koff[kt]);
        const f16x8 al = *(const f16x8*)(pA3 + m*8192 + koff[kt] + 16384);
        acc3[m] = __builtin_amdgcn_mfma_f32_32x32x16_f16(ah, bh, acc3[m], 0,0,0);
        acc3[m] = __builtin_amdgcn_mfma_f32_32x32x16_f16(ah, bl, acc3[m], 0,0,0);
        acc3[m] = __builtin_amdgcn_mfma_f32_32x32x16_f16(al, bh, acc3[m], 0,0,0);
      }
    }
  }

  // epilogue
  {
    const float b = ws[WS_B3F + ch];
    float x = 0.0f;
    #pragma unroll
    for (int m=0;m<2;m++){
      #pragma unroll
      for (int r=0;r<16;r++)
        x = fmaxf(x, acc3[m][r] + b);
    }
    x = fmaxf(x, __shfl_xor(x, 32, 64));
    if (lane < 32)
      atomicMax((unsigned*)(lat + cloud*128 + ch), __float_as_uint(x));
  }
}

// ---------------- FPS v5: register-pinned point state (R13, passing) ----------
__device__ __forceinline__ void fps_round(int r, int t, int wv,
                                          float bv, int bi, float bx, float by, float bz,
                                          float (*cv)[16], int (*ci)[16],
                                          float (*cx)[16], float (*cy)[16], float (*cz)[16],
                                          float* ws, float* out, int cloud,
                                          float& s0, float& s1, float& s2){
  float v = bv; int i = bi;
  #pragma unroll
  for (int m=1;m<64;m<<=1){
    float v2=__shfl_xor(v,m,64); int i2=__shfl_xor(i,m,64);
    if (v2 > v || (v2 == v && i2 < i)){ v=v2; i=i2; }
  }
  const int p = r & 1;
  if ((i >> 4) == t){ cv[p][wv]=v; ci[p][wv]=i; cx[p][wv]=bx; cy[p][wv]=by; cz[p][wv]=bz; }
  __syncthreads();
  float wvv = cv[p][0]; int wi = ci[p][0]; int slot = 0;
  #pragma unroll
  for (int e=1;e<16;e++){
    float v2=cv[p][e]; int i2=ci[p][e];
    if (v2 > wvv || (v2 == wvv && i2 < wi)){ wvv=v2; wi=i2; slot=e; }
  }
  s0 = cx[p][slot]; s1 = cy[p][slot]; s2 = cz[p][slot];
  if (t == 0){
    float* sw = ws + WS_SEL + cloud*48 + r*3;
    sw[0]=s0; sw[1]=s1; sw[2]=s2;
    size_t o = (cloud<B_) ? (size_t)(OUT_SRCKP + cloud*48 + r*3)
                          : (size_t)(OUT_TGTKP + (cloud-B_)*48 + r*3);
    out[o]=s0; out[o+1]=s1; out[o+2]=s2;
  }
}

__global__ __launch_bounds__(1024, 4) void fps_kernel(const float* __restrict__ src,
                                                      const float* __restrict__ tgt,
                                                      const float* __restrict__ kw1,
                                                      const float* __restrict__ kb1,
                                                      const float* __restrict__ kw2,
                                                      const float* __restrict__ kb2,
                                                      float* ws, float* out){
  const int cloud = blockIdx.x; const int t = threadIdx.x;
  const int wv = t >> 6;
  const int lane = t & 63;
  const float* base = (cloud < B_) ? (src + (size_t)cloud*N_*3)
                                   : (tgt + (size_t)cloud*N_*3 - (size_t)B_*N_*3);
  __shared__ alignas(16) float kpl[48];
  __shared__ alignas(16) float h[128];
  __shared__ float cv[2][16]; __shared__ int ci[2][16];
  __shared__ float cx[2][16]; __shared__ float cy[2][16]; __shared__ float cz[2][16];
  __shared__ float red[96];

  // load 16 consecutive points/thread via 12 float4 (coalesced)
  float px[16], py[16], pz[16];
  {
    float4 raw[12];
    const float4* b4 = (const float4*)(base + (size_t)t*48);
    #pragma unroll
    for (int q=0;q<12;q++) raw[q] = b4[q];
    #pragma unroll
    for (int q=0;q<4;q++){
      float4 va=raw[q*3], vb=raw[q*3+1], vc=raw[q*3+2];
      px[q*4  ]=va.x; py[q*4  ]=va.y; pz[q*4  ]=va.z;
      px[q*4+1]=va.w; py[q*4+1]=vb.x; pz[q*4+1]=vb.y;
      px[q*4+2]=vb.z; py[q*4+2]=vb.w; pz[q*4+2]=vc.x;
      px[q*4+3]=vc.y; py[q*4+3]=vc.z; pz[q*4+3]=vc.w;
    }
  }
  // pin point state in VGPRs: opaque to the compiler -> no remat-by-reload
  #pragma unroll
  for (int k=0;k<16;k++){
    asm volatile("" : "+v"(px[k]), "+v"(py[k]), "+v"(pz[k]));
  }

  // kp-MLP layer1 (order-identical; float4-batched loads)
  const float* lat = ws + WS_LAT + cloud*128;
  if (t < 128){
    float acc = kb1[t];
    const float4* w4 = (const float4*)(kw1 + t*128);
    const float4* l4 = (const float4*)lat;
    #pragma unroll 8
    for (int c4=0;c4<32;c4++){
      float4 wq=w4[c4], lq=l4[c4];
      acc = fmaf(lq.x, wq.x, acc);
      acc = fmaf(lq.y, wq.y, acc);
      acc = fmaf(lq.z, wq.z, acc);
      acc = fmaf(lq.w, wq.w, acc);
    }
    h[t] = fmaxf(acc, 0.0f);
  }
  __syncthreads();
  if (t < 48){
    float acc = kb2[t];
    const float4* w4 = (const float4*)(kw2 + t*128);
    #pragma unroll 8
    for (int c4=0;c4<32;c4++){
      float4 wq=w4[c4];
      float4 hq=*(const float4*)&h[c4*4];
      acc = fmaf(hq.x, wq.x, acc);
      acc = fmaf(hq.y, wq.y, acc);
      acc = fmaf(hq.z, wq.z, acc);
      acc = fmaf(hq.w, wq.w, acc);
    }
    kpl[t] = acc;
  }

  // src cloud min/max (exact: fmin/fmax order-independent)
  if (cloud < B_){
    float mn0=3.4e38f,mn1=3.4e38f,mn2=3.4e38f, mx0=-3.4e38f,mx1=-3.4e38f,mx2=-3.4e38f;
    #pragma unroll
    for (int k=0;k<16;k++){
      mn0=fminf(mn0,px[k]); mn1=fminf(mn1,py[k]); mn2=fminf(mn2,pz[k]);
      mx0=fmaxf(mx0,px[k]); mx1=fmaxf(mx1,py[k]); mx2=fmaxf(mx2,pz[k]);
    }
    #pragma unroll
    for (int m=1;m<64;m<<=1){
      mn0=fminf(mn0,__shfl_xor(mn0,m,64)); mx0=fmaxf(mx0,__shfl_xor(mx0,m,64));
      mn1=fminf(mn1,__shfl_xor(mn1,m,64)); mx1=fmaxf(mx1,__shfl_xor(mx1,m,64));
      mn2=fminf(mn2,__shfl_xor(mn2,m,64)); mx2=fmaxf(mx2,__shfl_xor(mx2,m,64));
    }
    if (lane==0){
      red[wv*6+0]=mn0; red[wv*6+1]=mn1; red[wv*6+2]=mn2;
      red[wv*6+3]=mx0; red[wv*6+4]=mx1; red[wv*6+5]=mx2;
    }
    __syncthreads();
    if (t < 6){
      float v = red[t];
      for (int e=1;e<16;e++){
        float v2 = red[e*6+t];
        v = (t<3) ? fminf(v,v2) : fmaxf(v,v2);
      }
      if (t<3) ws[WS_PMIN + cloud*3 + t] = v;
      else     ws[WS_PMAX + cloud*3 + (t-3)] = v;
    }
  }
  __syncthreads();   // kpl ready for all; red/minmax done

  // dmin over 16 keypoints, j-outer
  float mind[16];
  #pragma unroll
  for (int k=0;k<16;k++) mind[k] = 3.4028235e38f;
  for (int j=0;j<K_;j++){
    const float sx=kpl[j*3], sy=kpl[j*3+1], sz=kpl[j*3+2];
    #pragma unroll
    for (int k=0;k<16;k++)
      mind[k] = fminf(mind[k], dist2rn(px[k],py[k],pz[k], sx,sy,sz));
  }

  // round 0: argmax of keypoint-dmin
  float bv = -1.0f; int bi = 0; float bx=0.f, by=0.f, bz=0.f;
  #pragma unroll
  for (int k=0;k<16;k++){
    if (mind[k] > bv){ bv=mind[k]; bi=t*16+k; bx=px[k]; by=py[k]; bz=pz[k]; }
  }
  float s0, s1, s2;
  fps_round(0, t, wv, bv, bi, bx, by, bz, cv, ci, cx, cy, cz, ws, out, cloud, s0, s1, s2);

  // round 1: REPLACE (matches reference)
  bv = -1.0f; bi = 0;
  #pragma unroll
  for (int k=0;k<16;k++){
    float d = dist2rn(px[k],py[k],pz[k], s0,s1,s2);
    mind[k] = d;
    if (d > bv){ bv=d; bi=t*16+k; bx=px[k]; by=py[k]; bz=pz[k]; }
  }
  fps_round(1, t, wv, bv, bi, bx, by, bz, cv, ci, cx, cy, cz, ws, out, cloud, s0, s1, s2);

  // rounds 2..15
  for (int r=2; r<K_; ++r){
    bv = -1.0f; bi = 0;
    #pragma unroll
    for (int k=0;k<16;k++){
      float d = dist2rn(px[k],py[k],pz[k], s0,s1,s2);
      float m = fminf(mind[k], d);
      mind[k] = m;
      if (m > bv){ bv=m; bi=t*16+k; bx=px[k]; by=py[k]; bz=pz[k]; }
    }
    fps_round(r, t, wv, bv, bi, bx, by, bz, cv, ci, cx, cy, cz, ws, out, cloud, s0, s1, s2);
  }
}

// ---------------- cage MLP (redundant per block) + trilinear deform -----------
__global__ __launch_bounds__(256) void deform_kernel(const float* __restrict__ src,
                                                     const float* __restrict__ cw1,
                                                     const float* __restrict__ cb1,
                                                     const float* __restrict__ cw2,
                                                     const float* __restrict__ cb2,
                                                     const float* __restrict__ ws,
                                                     float* __restrict__ out){
  const int b = blockIdx.y;
  const int t = threadIdx.x;
  __shared__ float cf[1536];
  __shared__ alignas(16) float diff[48];
  __shared__ alignas(16) float hh[128];

  if (t<48) diff[t] = __fsub_rn(ws[WS_SEL + (B_+b)*48 + t], ws[WS_SEL + b*48 + t]);
  __syncthreads();
  if (t<128){
    const float4* w4 = (const float4*)(cw1 + t*48);
    float acc = cb1[t];
    #pragma unroll
    for (int j4=0;j4<12;j4++){
      float4 wq=w4[j4];
      float4 dq=*(const float4*)&diff[j4*4];
      acc = fmaf(dq.x, wq.x, acc);
      acc = fmaf(dq.y, wq.y, acc);
      acc = fmaf(dq.z, wq.z, acc);
      acc = fmaf(dq.w, wq.w, acc);
    }
    hh[t] = fmaxf(acc, 0.0f);
  }
  __syncthreads();
  for (int o = t; o < 1536; o += 256){
    const float4* w4 = (const float4*)(cw2 + o*128);
    float acc = cb2[o];
    #pragma unroll 8
    for (int c4=0;c4<32;c4++){
      float4 wq=w4[c4];
      float4 hq=*(const float4*)&hh[c4*4];
      acc = fmaf(hq.x, wq.x, acc);
      acc = fmaf(hq.y, wq.y, acc);
      acc = fmaf(hq.z, wq.z, acc);
      acc = fmaf(hq.w, wq.w, acc);
    }
    int flat = o/3, coord = o - flat*3;
    int u = flat>>6, v=(flat>>3)&7, z=flat&7;
    int g = (coord==0)?u:((coord==1)?v:z);
    float gv = (g==7)?1.0f:(float)g*(1.0f/7.0f);
    cf[o] = gv + acc;
  }
  __syncthreads();

  const float mn0 = ws[WS_PMIN+b*3+0], mn1 = ws[WS_PMIN+b*3+1], mn2 = ws[WS_PMIN+b*3+2];
  const float mx0 = ws[WS_PMAX+b*3+0], mx1 = ws[WS_PMAX+b*3+1], mx2 = ws[WS_PMAX+b*3+2];

  #pragma unroll
  for (int k=0;k<4;k++){
    const int n = blockIdx.x*1024 + k*256 + t;
    const float* p = src + ((size_t)b*N_ + n)*3;
    float pt[3]; int id[3]; float w[3];
    #pragma unroll
    for (int c=0;c<3;c++){
      float pv = p[c];
      float mnv = (c==0)?mn0:((c==1)?mn1:mn2);
      float mxv = (c==0)?mx0:((c==1)?mx1:mx2);
      float denom = __fadd_rn(__fsub_rn(mxv, mnv), 1e-6f);
      float tc = __fmul_rn(__fdiv_rn(__fsub_rn(pv, mnv), denom), 7.0f);
      int ic = (int)tc; ic = min(max(ic,0),6);
      pt[c]=pv; id[c]=ic; w[c]=__fsub_rn(tc, (float)ic);
    }
    const int flat = (id[0]<<6) + (id[1]<<3) + id[2];
    const float* c000 = cf + flat*3;
    const float wx=w[0], wy=w[1], wz=w[2];
    const float ux=__fsub_rn(1.0f,wx), uy=__fsub_rn(1.0f,wy), uz=__fsub_rn(1.0f,wz);
    const float w000=__fmul_rn(__fmul_rn(ux,uy),uz);
    const float w100=__fmul_rn(__fmul_rn(wx,uy),uz);
    const float w010=__fmul_rn(__fmul_rn(ux,wy),uz);
    const float w110=__fmul_rn(__fmul_rn(wx,wy),uz);
    const float w001=__fmul_rn(__fmul_rn(ux,uy),wz);
    const float w101=__fmul_rn(__fmul_rn(wx,uy),wz);
    const float w011=__fmul_rn(__fmul_rn(ux,wy),wz);
    const float w111=__fmul_rn(__fmul_rn(wx,wy),wz);
    #pragma unroll
    for (int c=0;c<3;c++){
      float d = __fmul_rn(w000, c000[c]);
      d = __fadd_rn(d, __fmul_rn(w100, c000[192+c]));
      d = __fadd_rn(d, __fmul_rn(w010, c000[24+c]));
      d = __fadd_rn(d, __fmul_rn(w110, c000[216+c]));
      d = __fadd_rn(d, __fmul_rn(w001, c000[3+c]));
      d = __fadd_rn(d, __fmul_rn(w101, c000[195+c]));
      d = __fadd_rn(d, __fmul_rn(w011, c000[27+c]));
      d = __fadd_rn(d, __fmul_rn(w111, c000[219+c]));
      out[((size_t)b*N_+n)*3 + c] = __fadd_rn(pt[c], d);
    }
  }
}

// ---------------- launch ------------------------------------------------------
extern "C" void kernel_launch(void* const* d_in, const int* in_sizes, int n_in,
                              void* d_out, int out_size, void* d_ws, size_t ws_size,
                              hipStream_t stream){
  const float* src = (const float*)d_in[0];
  const float* tgt = (const float*)d_in[1];
  float* ws = (float*)d_ws;
  float* out = (float*)d_out;

  EncW ew;
  ew.w1 =(const float*)d_in[2];  ew.b1 =(const float*)d_in[3];
  ew.g1 =(const float*)d_in[4];  ew.be1=(const float*)d_in[5];
  ew.m1 =(const float*)d_in[6];  ew.v1 =(const float*)d_in[7];
  ew.w2 =(const float*)d_in[8];  ew.b2 =(const float*)d_in[9];
  ew.g2 =(const float*)d_in[10]; ew.be2=(const float*)d_in[11];
  ew.m2 =(const float*)d_in[12]; ew.v2 =(const float*)d_in[13];
  ew.w3 =(const float*)d_in[14]; ew.b3 =(const float*)d_in[15];
  ew.g3 =(const float*)d_in[16]; ew.be3=(const float*)d_in[17];
  ew.m3 =(const float*)d_in[18]; ew.v3 =(const float*)d_in[19];

  prep_kernel<<<128, 256, 0, stream>>>(ew, ws);
  encode_kernel<<<dim3(256,32), 256, 0, stream>>>(src, tgt, ws, ws + WS_LAT);
  fps_kernel<<<32, 1024, 0, stream>>>(src, tgt,
      (const float*)d_in[20], (const float*)d_in[21],
      (const float*)d_in[22], (const float*)d_in[23], ws, out);
  deform_kernel<<<dim3(16,16), 256, 0, stream>>>(src,
      (const float*)d_in[24], (const float*)d_in[25],
      (const float*)d_in[26], (const float*)d_in[27], ws, out);
}

// Round 16
// 293.537 us; speedup vs baseline: 1.1417x; 1.0073x over previous
//
#include <hip/hip_runtime.h>

#define B_ 16
#define N_ 16384
#define K_ 16

// ---- workspace layout (float offsets) ----
enum : int {
  WS_LAT  = 0,      // 32 x 128 latent (f32, atomicMax-as-uint, relu>=0)
  WS_SEL  = 5632,   // 32 x 48 selected keypoints
  WS_PMIN = 7168,   // 16 x 3
  WS_PMAX = 7216,   // 16 x 3
  WS_CF   = 7264,   // (unused; cage corners computed in deform)
  WS_W1F  = 31840,  // 64 x 3  bn-folded (fp32)
  WS_B1F  = 32032,  // 64
  // split-f16 B-fragment tables (32x32x16 MFMA layout), built by prep:
  WS_WB2H = 32096,  // 8192 f16: layer2 B hi frags [wn*4+kt][lane][8]
  WS_WB2L = 36192,  // 8192 f16
  WS_B2F  = 40288,  // 128 fp32 folded bias
  WS_WB3H = 40416,  // 16384 f16: layer3 B hi frags [wn*8+kt][lane][8]
  WS_B3F  = 56800,  // 128 fp32 folded bias
  WS_WB3L = 56928,  // 16384 f16
  WS_END  = 73312
};

enum : int { OUT_DEF=0, OUT_SRCKP=786432, OUT_TGTKP=787200 };

typedef _Float16 f16x8 __attribute__((ext_vector_type(8)));
typedef _Float16 f16x4 __attribute__((ext_vector_type(4)));
typedef _Float16 f16x2 __attribute__((ext_vector_type(2)));
typedef float    f32x16 __attribute__((ext_vector_type(16)));

__device__ __forceinline__ float dist2rn(float px,float py,float pz,float sx,float sy,float sz){
  float dx=__fsub_rn(px,sx), dy=__fsub_rn(py,sy), dz=__fsub_rn(pz,sz);
  return __fadd_rn(__fadd_rn(__fmul_rn(dx,dx),__fmul_rn(dy,dy)),__fmul_rn(dz,dz));
}

// concat two b64 LDS loads into one MFMA A-operand
__device__ __forceinline__ f16x8 ldA2(const char* p0, const char* p1){
  f16x4 a = *(const f16x4*)p0;
  f16x4 b = *(const f16x4*)p1;
  return __builtin_shufflevector(a, b, 0,1,2,3,4,5,6,7);
}

// ---------------- prep: fold BN into encoder weights + split-f16 frags --------
struct EncW {
  const float *w1,*b1,*g1,*be1,*m1,*v1;
  const float *w2,*b2,*g2,*be2,*m2,*v2;
  const float *w3,*b3,*g3,*be3,*m3,*v3;
};

__device__ __forceinline__ float bn_scale(const float* g, const float* v, int ch){
  return g[ch] * (1.0f / sqrtf(v[ch] + 1e-5f));
}

__global__ void prep_kernel(EncW a, float* ws){
  const int stride = gridDim.x*blockDim.x;
  const int tid = blockIdx.x*blockDim.x + threadIdx.x;
  for (int i=tid;i<4096;i+=stride)            // zero latent (atomicMax target)
    ws[WS_LAT+i] = 0.0f;
  for (int i=tid;i<192;i+=stride){            // W1F
    int o=i/3;
    ws[WS_W1F+i] = a.w1[i] * bn_scale(a.g1,a.v1,o);
  }
  for (int i=tid;i<64;i+=stride){             // B1F
    float s = bn_scale(a.g1,a.v1,i);
    ws[WS_B1F+i] = (a.b1[i] - a.m1[i])*s + a.be1[i];
  }
  // layer2 B-frags for 32x32x16: lane l holds B[k=kt*16+(l>>5)*8+j][col=wn*32+(l&31)]
  for (int i=tid;i<8192;i+=stride){
    int j = i & 7, frag = i >> 3;
    int l = frag & 63, wk = frag >> 6;        // wk = wn*4 + kt, <16
    int kt = wk & 3, wn = wk >> 2;
    int c = kt*16 + ((l>>5)<<3) + j;          // 0..63 in-channel (K)
    int o = wn*32 + (l&31);                   // 0..127 out-channel (N)
    float v = a.w2[o*64+c] * bn_scale(a.g2,a.v2,o);
    _Float16 h = (_Float16)v;
    ((_Float16*)(ws+WS_WB2H))[i] = h;
    ((_Float16*)(ws+WS_WB2L))[i] = (_Float16)(v - (float)h);
  }
  for (int i=tid;i<128;i+=stride){
    float s = bn_scale(a.g2,a.v2,i);
    ws[WS_B2F+i] = (a.b2[i] - a.m2[i])*s + a.be2[i];
  }
  // layer3 B-frags (16384 elements = 128x128)
  for (int i=tid;i<16384;i+=stride){
    int j = i & 7, frag = i >> 3;
    int l = frag & 63, wk = frag >> 6;        // wk = wn*8 + kt, <32
    int kt = wk & 7, wn = wk >> 3;
    int c = kt*16 + ((l>>5)<<3) + j;          // 0..127 in-channel (K)
    int o = wn*32 + (l&31);                   // 0..127 out-channel (N)
    float v = a.w3[o*128+c] * bn_scale(a.g3,a.v3,o);
    _Float16 h = (_Float16)v;
    ((_Float16*)(ws+WS_WB3H))[i] = h;
    ((_Float16*)(ws+WS_WB3L))[i] = (_Float16)(v - (float)h);
  }
  for (int i=tid;i<128;i+=stride){
    float s = bn_scale(a.g3,a.v3,i);
    ws[WS_B3F+i] = (a.b3[i] - a.m3[i])*s + a.be3[i];
  }
}

// ---------------- encoder v16: 4-bit LDS swizzle + b64 A-reads ----------------
// R15 counters: SQ_LDS_BANK_CONFLICT 9.4M (~15% of encode cycles). Cause: A-row
// strides (128/256B) are 0 mod 32 banks, and b128's 16B alignment caps the XOR
// swizzle at 3 bank bits -> 8 groups for 32 lanes = structural 4-way conflict.
// v16: A-fragment reads become 2x ds_read_b64 (8B-aligned -> 4 swizzlable bank
// bits), swizzle (row&15)<<2 in f16 units -> 16 groups, 2 lanes/group (free per
// m136). Write sides use the identical layout -> values/MFMA order bit-identical.
__global__ __launch_bounds__(256, 5) void encode_kernel(const float* __restrict__ src,
                                                        const float* __restrict__ tgt,
                                                        const float* __restrict__ ws,
                                                        float* __restrict__ lat){
  const int cloud = blockIdx.y;
  const int tile  = blockIdx.x;              // 256 tiles/cloud, 64 pts each
  const int t = threadIdx.x;
  const int lane = t & 63;
  const int wn = __builtin_amdgcn_readfirstlane(t >> 6);   // 0..3: cols wn*32..+31
  const int l31 = lane & 31;
  const int hb  = lane >> 5;                 // 0/1: k-group / +4-row half
  const int swz4 = (l31 & 15) << 2;          // f16-index bits 2-5

  __shared__ alignas(16) _Float16 A[16384];  // 32KB

  const float* base = ((cloud < B_) ? (src + (size_t)cloud*N_*3)
                                    : (tgt + (size_t)(cloud-B_)*N_*3))
                      + (size_t)tile*64*3;

  // ---- prefetch layer2 B-frags (latency hides under layer1) ----
  f16x8 b2h[4], b2l[4];
  {
    const _Float16* wb2h = (const _Float16*)(ws + WS_WB2H);
    const _Float16* wb2l = (const _Float16*)(ws + WS_WB2L);
    #pragma unroll
    for (int kt=0; kt<4; kt++){
      const int fi = ((wn*4 + kt)*64 + lane)*8;
      b2h[kt] = *(const f16x8*)(wb2h + fi);
      b2l[kt] = *(const f16x8*)(wb2l + fi);
    }
  }

  // ---- layer 1 (3->64), fp32 VALU; writes use 4-bit swizzle ----
  {
    const int pt = t >> 2, q = t & 3;        // pt 0..63
    const float x = base[pt*3+0], y = base[pt*3+1], z = base[pt*3+2];
    const float* w1 = ws + WS_W1F;
    const float* b1 = ws + WS_B1F;
    const int sw1 = (pt & 15) << 2;          // bits 2-5; keeps f16x2 pairing (bit 0)
    _Float16* AH1 = A;
    _Float16* AL1 = A + 4096;
    #pragma unroll
    for (int cc = 0; cc < 16; cc += 2){
      const int o = q*16 + cc;
      float v0 = fmaf(w1[o*3+2], z, fmaf(w1[o*3+1], y, w1[o*3+0]*x)) + b1[o];
      float v1 = fmaf(w1[o*3+5], z, fmaf(w1[o*3+4], y, w1[o*3+3]*x)) + b1[o+1];
      v0 = fmaxf(v0, 0.0f); v1 = fmaxf(v1, 0.0f);
      f16x2 h, l;
      h[0] = (_Float16)v0;              h[1] = (_Float16)v1;
      l[0] = (_Float16)(v0 - (float)h[0]); l[1] = (_Float16)(v1 - (float)h[1]);
      const int idx = pt*64 + (o ^ sw1);
      *(f16x2*)&AH1[idx] = h;
      *(f16x2*)&AL1[idx] = l;
    }
  }

  // per-(kt,half) byte offsets, shared by layer2 (kt<4) and layer3 (kt<8)
  int koff[8][2];
  #pragma unroll
  for (int kt=0; kt<8; kt++){
    #pragma unroll
    for (int h=0; h<2; h++)
      koff[kt][h] = (((kt*16) | (hb*8) | (h*4)) ^ swz4) << 1;
  }

  __syncthreads();

  // ---- layer 2 (64->128): 3-term split, 32x32x16, b64 A-reads ----
  f32x16 acc2[2];
  #pragma unroll
  for (int e=0;e<16;e++){ acc2[0][e]=0.0f; acc2[1][e]=0.0f; }
  {
    const char* pA2 = (const char*)A + l31*128;   // row stride 128B (64 f16)
    #pragma unroll
    for (int kt=0; kt<4; kt++){
      #pragma unroll
      for (int m=0;m<2;m++){
        const char* p = pA2 + m*4096;
        const f16x8 ah = ldA2(p + koff[kt][0],        p + koff[kt][1]);
        const f16x8 al = ldA2(p + koff[kt][0] + 8192, p + koff[kt][1] + 8192);
        acc2[m] = __builtin_amdgcn_mfma_f32_32x32x16_f16(ah, b2h[kt], acc2[m], 0,0,0);
        acc2[m] = __builtin_amdgcn_mfma_f32_32x32x16_f16(ah, b2l[kt], acc2[m], 0,0,0);
        acc2[m] = __builtin_amdgcn_mfma_f32_32x32x16_f16(al, b2h[kt], acc2[m], 0,0,0);
      }
    }
  }
  __syncthreads();

  // ---- h2 = relu(acc2 + b2): split hi/lo -> LDS (4-bit swizzle layout) ----
  const int ch = wn*32 + l31;
  {
    const float b = ws[WS_B2F + ch];
    // row = m*32 + (r4 + 4hb) + 8rq ; row&15 = (r4+4hb) + 8*(rq&1)
    int colb[4][2];
    #pragma unroll
    for (int r4=0;r4<4;r4++){
      const int row7 = r4 + 4*hb;            // 0..7
      colb[r4][0] = (ch ^ (row7<<2)) << 1;
      colb[r4][1] = ((ch ^ (row7<<2)) << 1) ^ 64;   // ^(8<<2) f16 -> ^64 bytes
    }
    #pragma unroll
    for (int r4=0;r4<4;r4++){
      #pragma unroll
      for (int rq=0;rq<4;rq++){
        const int reg = rq*4 + r4;
        const int rowb = (r4 + 4*hb)*256 + rq*2048;
        #pragma unroll
        for (int m=0;m<2;m++){
          const float v = fmaxf(acc2[m][reg] + b, 0.0f);
          const _Float16 hi = (_Float16)v;
          const _Float16 lo = (_Float16)(v - (float)hi);
          char* pw = (char*)A + rowb + m*8192 + colb[r4][rq&1];
          *(_Float16*)(pw) = hi;
          *(_Float16*)(pw + 16384) = lo;
        }
      }
    }
  }
  __syncthreads();

  // ---- layer 3 (128->128): 3-term split, 32x32x16, b64 A-reads ----
  f32x16 acc3[2];
  #pragma unroll
  for (int e=0;e<16;e++){ acc3[0][e]=0.0f; acc3[1][e]=0.0f; }
  {
    const _Float16* wb3h = (const _Float16*)(ws + WS_WB3H);
    const _Float16* wb3l = (const _Float16*)(ws + WS_WB3L);
    const char* pA3 = (const char*)A + l31*256;   // row stride 256B (128 f16)
    #pragma unroll
    for (int kt=0; kt<8; kt++){
      const int fi = ((wn*8 + kt)*64 + lane)*8;
      const f16x8 bh = *(const f16x8*)(wb3h + fi);
      const f16x8 bl = *(const f16x8*)(wb3l + fi);
      #pragma unroll
      for (int m=0;m<2;m++){
        const char* p = pA3 + m*8192;
        const f16x8 ah = ldA2(p + koff[kt][0],         p + koff[kt][1]);
        const f16x8 al = ldA2(p + koff[kt][0] + 16384, p + koff[kt][1] + 16384);
        acc3[m] = __builtin_amdgcn_mfma_f32_32x32x16_f16(ah, bh, acc3[m], 0,0,0);
        acc3[m] = __builtin_amdgcn_mfma_f32_32x32x16_f16(ah, bl, acc3[m], 0,0,0);
        acc3[m] = __builtin_amdgcn_mfma_f32_32x32x16_f16(al, bh, acc3[m], 0,0,0);
      }
    }
  }

  // epilogue
  {
    const float b = ws[WS_B3F + ch];
    float x = 0.0f;
    #pragma unroll
    for (int m=0;m<2;m++){
      #pragma unroll
      for (int r=0;r<16;r++)
        x = fmaxf(x, acc3[m][r] + b);
    }
    x = fmaxf(x, __shfl_xor(x, 32, 64));
    if (lane < 32)
      atomicMax((unsigned*)(lat + cloud*128 + ch), __float_as_uint(x));
  }
}

// ---------------- FPS v5: register-pinned point state (R13, passing) ----------
__device__ __forceinline__ void fps_round(int r, int t, int wv,
                                          float bv, int bi, float bx, float by, float bz,
                                          float (*cv)[16], int (*ci)[16],
                                          float (*cx)[16], float (*cy)[16], float (*cz)[16],
                                          float* ws, float* out, int cloud,
                                          float& s0, float& s1, float& s2){
  float v = bv; int i = bi;
  #pragma unroll
  for (int m=1;m<64;m<<=1){
    float v2=__shfl_xor(v,m,64); int i2=__shfl_xor(i,m,64);
    if (v2 > v || (v2 == v && i2 < i)){ v=v2; i=i2; }
  }
  const int p = r & 1;
  if ((i >> 4) == t){ cv[p][wv]=v; ci[p][wv]=i; cx[p][wv]=bx; cy[p][wv]=by; cz[p][wv]=bz; }
  __syncthreads();
  float wvv = cv[p][0]; int wi = ci[p][0]; int slot = 0;
  #pragma unroll
  for (int e=1;e<16;e++){
    float v2=cv[p][e]; int i2=ci[p][e];
    if (v2 > wvv || (v2 == wvv && i2 < wi)){ wvv=v2; wi=i2; slot=e; }
  }
  s0 = cx[p][slot]; s1 = cy[p][slot]; s2 = cz[p][slot];
  if (t == 0){
    float* sw = ws + WS_SEL + cloud*48 + r*3;
    sw[0]=s0; sw[1]=s1; sw[2]=s2;
    size_t o = (cloud<B_) ? (size_t)(OUT_SRCKP + cloud*48 + r*3)
                          : (size_t)(OUT_TGTKP + (cloud-B_)*48 + r*3);
    out[o]=s0; out[o+1]=s1; out[o+2]=s2;
  }
}

__global__ __launch_bounds__(1024, 4) void fps_kernel(const float* __restrict__ src,
                                                      const float* __restrict__ tgt,
                                                      const float* __restrict__ kw1,
                                                      const float* __restrict__ kb1,
                                                      const float* __restrict__ kw2,
                                                      const float* __restrict__ kb2,
                                                      float* ws, float* out){
  const int cloud = blockIdx.x; const int t = threadIdx.x;
  const int wv = t >> 6;
  const int lane = t & 63;
  const float* base = (cloud < B_) ? (src + (size_t)cloud*N_*3)
                                   : (tgt + (size_t)cloud*N_*3 - (size_t)B_*N_*3);
  __shared__ alignas(16) float kpl[48];
  __shared__ alignas(16) float h[128];
  __shared__ float cv[2][16]; __shared__ int ci[2][16];
  __shared__ float cx[2][16]; __shared__ float cy[2][16]; __shared__ float cz[2][16];
  __shared__ float red[96];

  // load 16 consecutive points/thread via 12 float4 (coalesced)
  float px[16], py[16], pz[16];
  {
    float4 raw[12];
    const float4* b4 = (const float4*)(base + (size_t)t*48);
    #pragma unroll
    for (int q=0;q<12;q++) raw[q] = b4[q];
    #pragma unroll
    for (int q=0;q<4;q++){
      float4 va=raw[q*3], vb=raw[q*3+1], vc=raw[q*3+2];
      px[q*4  ]=va.x; py[q*4  ]=va.y; pz[q*4  ]=va.z;
      px[q*4+1]=va.w; py[q*4+1]=vb.x; pz[q*4+1]=vb.y;
      px[q*4+2]=vb.z; py[q*4+2]=vb.w; pz[q*4+2]=vc.x;
      px[q*4+3]=vc.y; py[q*4+3]=vc.z; pz[q*4+3]=vc.w;
    }
  }
  // pin point state in VGPRs: opaque to the compiler -> no remat-by-reload
  #pragma unroll
  for (int k=0;k<16;k++){
    asm volatile("" : "+v"(px[k]), "+v"(py[k]), "+v"(pz[k]));
  }

  // kp-MLP layer1 (order-identical; float4-batched loads)
  const float* lat = ws + WS_LAT + cloud*128;
  if (t < 128){
    float acc = kb1[t];
    const float4* w4 = (const float4*)(kw1 + t*128);
    const float4* l4 = (const float4*)lat;
    #pragma unroll 8
    for (int c4=0;c4<32;c4++){
      float4 wq=w4[c4], lq=l4[c4];
      acc = fmaf(lq.x, wq.x, acc);
      acc = fmaf(lq.y, wq.y, acc);
      acc = fmaf(lq.z, wq.z, acc);
      acc = fmaf(lq.w, wq.w, acc);
    }
    h[t] = fmaxf(acc, 0.0f);
  }
  __syncthreads();
  if (t < 48){
    float acc = kb2[t];
    const float4* w4 = (const float4*)(kw2 + t*128);
    #pragma unroll 8
    for (int c4=0;c4<32;c4++){
      float4 wq=w4[c4];
      float4 hq=*(const float4*)&h[c4*4];
      acc = fmaf(hq.x, wq.x, acc);
      acc = fmaf(hq.y, wq.y, acc);
      acc = fmaf(hq.z, wq.z, acc);
      acc = fmaf(hq.w, wq.w, acc);
    }
    kpl[t] = acc;
  }

  // src cloud min/max (exact: fmin/fmax order-independent)
  if (cloud < B_){
    float mn0=3.4e38f,mn1=3.4e38f,mn2=3.4e38f, mx0=-3.4e38f,mx1=-3.4e38f,mx2=-3.4e38f;
    #pragma unroll
    for (int k=0;k<16;k++){
      mn0=fminf(mn0,px[k]); mn1=fminf(mn1,py[k]); mn2=fminf(mn2,pz[k]);
      mx0=fmaxf(mx0,px[k]); mx1=fmaxf(mx1,py[k]); mx2=fmaxf(mx2,pz[k]);
    }
    #pragma unroll
    for (int m=1;m<64;m<<=1){
      mn0=fminf(mn0,__shfl_xor(mn0,m,64)); mx0=fmaxf(mx0,__shfl_xor(mx0,m,64));
      mn1=fminf(mn1,__shfl_xor(mn1,m,64)); mx1=fmaxf(mx1,__shfl_xor(mx1,m,64));
      mn2=fminf(mn2,__shfl_xor(mn2,m,64)); mx2=fmaxf(mx2,__shfl_xor(mx2,m,64));
    }
    if (lane==0){
      red[wv*6+0]=mn0; red[wv*6+1]=mn1; red[wv*6+2]=mn2;
      red[wv*6+3]=mx0; red[wv*6+4]=mx1; red[wv*6+5]=mx2;
    }
    __syncthreads();
    if (t < 6){
      float v = red[t];
      for (int e=1;e<16;e++){
        float v2 = red[e*6+t];
        v = (t<3) ? fminf(v,v2) : fmaxf(v,v2);
      }
      if (t<3) ws[WS_PMIN + cloud*3 + t] = v;
      else     ws[WS_PMAX + cloud*3 + (t-3)] = v;
    }
  }
  __syncthreads();   // kpl ready for all; red/minmax done

  // dmin over 16 keypoints, j-outer
  float mind[16];
  #pragma unroll
  for (int k=0;k<16;k++) mind[k] = 3.4028235e38f;
  for (int j=0;j<K_;j++){
    const float sx=kpl[j*3], sy=kpl[j*3+1], sz=kpl[j*3+2];
    #pragma unroll
    for (int k=0;k<16;k++)
      mind[k] = fminf(mind[k], dist2rn(px[k],py[k],pz[k], sx,sy,sz));
  }

  // round 0: argmax of keypoint-dmin
  float bv = -1.0f; int bi = 0; float bx=0.f, by=0.f, bz=0.f;
  #pragma unroll
  for (int k=0;k<16;k++){
    if (mind[k] > bv){ bv=mind[k]; bi=t*16+k; bx=px[k]; by=py[k]; bz=pz[k]; }
  }
  float s0, s1, s2;
  fps_round(0, t, wv, bv, bi, bx, by, bz, cv, ci, cx, cy, cz, ws, out, cloud, s0, s1, s2);

  // round 1: REPLACE (matches reference)
  bv = -1.0f; bi = 0;
  #pragma unroll
  for (int k=0;k<16;k++){
    float d = dist2rn(px[k],py[k],pz[k], s0,s1,s2);
    mind[k] = d;
    if (d > bv){ bv=d; bi=t*16+k; bx=px[k]; by=py[k]; bz=pz[k]; }
  }
  fps_round(1, t, wv, bv, bi, bx, by, bz, cv, ci, cx, cy, cz, ws, out, cloud, s0, s1, s2);

  // rounds 2..15
  for (int r=2; r<K_; ++r){
    bv = -1.0f; bi = 0;
    #pragma unroll
    for (int k=0;k<16;k++){
      float d = dist2rn(px[k],py[k],pz[k], s0,s1,s2);
      float m = fminf(mind[k], d);
      mind[k] = m;
      if (m > bv){ bv=m; bi=t*16+k; bx=px[k]; by=py[k]; bz=pz[k]; }
    }
    fps_round(r, t, wv, bv, bi, bx, by, bz, cv, ci, cx, cy, cz, ws, out, cloud, s0, s1, s2);
  }
}

// ---------------- cage MLP (redundant per block) + trilinear deform -----------
__global__ __launch_bounds__(256) void deform_kernel(const float* __restrict__ src,
                                                     const float* __restrict__ cw1,
                                                     const float* __restrict__ cb1,
                                                     const float* __restrict__ cw2,
                                                     const float* __restrict__ cb2,
                                                     const float* __restrict__ ws,
                                                     float* __restrict__ out){
  const int b = blockIdx.y;
  const int t = threadIdx.x;
  __shared__ float cf[1536];
  __shared__ alignas(16) float diff[48];
  __shared__ alignas(16) float hh[128];

  if (t<48) diff[t] = __fsub_rn(ws[WS_SEL + (B_+b)*48 + t], ws[WS_SEL + b*48 + t]);
  __syncthreads();
  if (t<128){
    const float4* w4 = (const float4*)(cw1 + t*48);
    float acc = cb1[t];
    #pragma unroll
    for (int j4=0;j4<12;j4++){
      float4 wq=w4[j4];
      float4 dq=*(const float4*)&diff[j4*4];
      acc = fmaf(dq.x, wq.x, acc);
      acc = fmaf(dq.y, wq.y, acc);
      acc = fmaf(dq.z, wq.z, acc);
      acc = fmaf(dq.w, wq.w, acc);
    }
    hh[t] = fmaxf(acc, 0.0f);
  }
  __syncthreads();
  for (int o = t; o < 1536; o += 256){
    const float4* w4 = (const float4*)(cw2 + o*128);
    float acc = cb2[o];
    #pragma unroll 8
    for (int c4=0;c4<32;c4++){
      float4 wq=w4[c4];
      float4 hq=*(const float4*)&hh[c4*4];
      acc = fmaf(hq.x, wq.x, acc);
      acc = fmaf(hq.y, wq.y, acc);
      acc = fmaf(hq.z, wq.z, acc);
      acc = fmaf(hq.w, wq.w, acc);
    }
    int flat = o/3, coord = o - flat*3;
    int u = flat>>6, v=(flat>>3)&7, z=flat&7;
    int g = (coord==0)?u:((coord==1)?v:z);
    float gv = (g==7)?1.0f:(float)g*(1.0f/7.0f);
    cf[o] = gv + acc;
  }
  __syncthreads();

  const float mn0 = ws[WS_PMIN+b*3+0], mn1 = ws[WS_PMIN+b*3+1], mn2 = ws[WS_PMIN+b*3+2];
  const float mx0 = ws[WS_PMAX+b*3+0], mx1 = ws[WS_PMAX+b*3+1], mx2 = ws[WS_PMAX+b*3+2];

  #pragma unroll
  for (int k=0;k<4;k++){
    const int n = blockIdx.x*1024 + k*256 + t;
    const float* p = src + ((size_t)b*N_ + n)*3;
    float pt[3]; int id[3]; float w[3];
    #pragma unroll
    for (int c=0;c<3;c++){
      float pv = p[c];
      float mnv = (c==0)?mn0:((c==1)?mn1:mn2);
      float mxv = (c==0)?mx0:((c==1)?mx1:mx2);
      float denom = __fadd_rn(__fsub_rn(mxv, mnv), 1e-6f);
      float tc = __fmul_rn(__fdiv_rn(__fsub_rn(pv, mnv), denom), 7.0f);
      int ic = (int)tc; ic = min(max(ic,0),6);
      pt[c]=pv; id[c]=ic; w[c]=__fsub_rn(tc, (float)ic);
    }
    const int flat = (id[0]<<6) + (id[1]<<3) + id[2];
    const float* c000 = cf + flat*3;
    const float wx=w[0], wy=w[1], wz=w[2];
    const float ux=__fsub_rn(1.0f,wx), uy=__fsub_rn(1.0f,wy), uz=__fsub_rn(1.0f,wz);
    const float w000=__fmul_rn(__fmul_rn(ux,uy),uz);
    const float w100=__fmul_rn(__fmul_rn(wx,uy),uz);
    const float w010=__fmul_rn(__fmul_rn(ux,wy),uz);
    const float w110=__fmul_rn(__fmul_rn(wx,wy),uz);
    const float w001=__fmul_rn(__fmul_rn(ux,uy),wz);
    const float w101=__fmul_rn(__fmul_rn(wx,uy),wz);
    const float w011=__fmul_rn(__fmul_rn(ux,wy),wz);
    const float w111=__fmul_rn(__fmul_rn(wx,wy),wz);
    #pragma unroll
    for (int c=0;c<3;c++){
      float d = __fmul_rn(w000, c000[c]);
      d = __fadd_rn(d, __fmul_rn(w100, c000[192+c]));
      d = __fadd_rn(d, __fmul_rn(w010, c000[24+c]));
      d = __fadd_rn(d, __fmul_rn(w110, c000[216+c]));
      d = __fadd_rn(d, __fmul_rn(w001, c000[3+c]));
      d = __fadd_rn(d, __fmul_rn(w101, c000[195+c]));
      d = __fadd_rn(d, __fmul_rn(w011, c000[27+c]));
      d = __fadd_rn(d, __fmul_rn(w111, c000[219+c]));
      out[((size_t)b*N_+n)*3 + c] = __fadd_rn(pt[c], d);
    }
  }
}

// ---------------- launch ------------------------------------------------------
extern "C" void kernel_launch(void* const* d_in, const int* in_sizes, int n_in,
                              void* d_out, int out_size, void* d_ws, size_t ws_size,
                              hipStream_t stream){
  const float* src = (const float*)d_in[0];
  const float* tgt = (const float*)d_in[1];
  float* ws = (float*)d_ws;
  float* out = (float*)d_out;

  EncW ew;
  ew.w1 =(const float*)d_in[2];  ew.b1 =(const float*)d_in[3];
  ew.g1 =(const float*)d_in[4];  ew.be1=(const float*)d_in[5];
  ew.m1 =(const float*)d_in[6];  ew.v1 =(const float*)d_in[7];
  ew.w2 =(const float*)d_in[8];  ew.b2 =(const float*)d_in[9];
  ew.g2 =(const float*)d_in[10]; ew.be2=(const float*)d_in[11];
  ew.m2 =(const float*)d_in[12]; ew.v2 =(const float*)d_in[13];
  ew.w3 =(const float*)d_in[14]; ew.b3 =(const float*)d_in[15];
  ew.g3 =(const float*)d_in[16]; ew.be3=(const float*)d_in[17];
  ew.m3 =(const float*)d_in[18]; ew.v3 =(const float*)d_in[19];

  prep_kernel<<<128, 256, 0, stream>>>(ew, ws);
  encode_kernel<<<dim3(256,32), 256, 0, stream>>>(src, tgt, ws, ws + WS_LAT);
  fps_kernel<<<32, 1024, 0, stream>>>(src, tgt,
      (const float*)d_in[20], (const float*)d_in[21],
      (const float*)d_in[22], (const float*)d_in[23], ws, out);
  deform_kernel<<<dim3(16,16), 256, 0, stream>>>(src,
      (const float*)d_in[24], (const float*)d_in[25],
      (const float*)d_in[26], (const float*)d_in[27], ws, out);
}